// Round 7
// baseline (51.136 us; speedup 1.0000x reference)
//
#include <hip/hip_runtime.h>
#include <hip/hip_bf16.h>

// Causal conv1d as bf16 MFMA GEMM — counted-vmcnt pipeline at 2 blocks/CU.
// out[b,h,t] = sum_{c,k} x[b,c,t+k-3] * W[h, c*4+k] + bias[h]
// B=8, C=256, T=4096, H=512, K=4.

#define Bb 8
#define Cc 256
#define Tt 4096
#define Hh 512
#define Kk 4

typedef __attribute__((ext_vector_type(8))) short bf16x8;
typedef __attribute__((ext_vector_type(4))) float f32x4;

#define WS_XT_OFF   0
#define WS_WT_OFF   16777216
#define WS_ZERO_OFF 17825792
#define WS_NEEDED   17826816ULL

__device__ __forceinline__ void gload16(const void* g, void* l) {
    __builtin_amdgcn_global_load_lds(
        (const __attribute__((address_space(1))) void*)g,
        (__attribute__((address_space(3))) void*)l, 16, 0, 0);
}

// ---------- merged prep: xT transpose (blocks 0..2047) + Wt pack (2048..4095) ----------
__global__ __launch_bounds__(256) void prep_kernel(const float* __restrict__ x,
                                                   const float* __restrict__ W,
                                                   __hip_bfloat16* __restrict__ xT,
                                                   __hip_bfloat16* __restrict__ Wt,
                                                   float* __restrict__ zeros) {
    __shared__ __hip_bfloat16 tile[64][72];
    const int bid = blockIdx.x;
    if (bid < 2048) {
        const int t0 = (bid & 63) * 64, c0 = ((bid >> 6) & 3) * 64, b = bid >> 8;
        const int lt = threadIdx.x & 63, lw = threadIdx.x >> 6;
#pragma unroll
        for (int i = 0; i < 16; ++i) {
            int cc = lw + i * 4;
            tile[cc][lt] = __float2bfloat16(x[((size_t)(b * Cc + c0 + cc)) * Tt + t0 + lt]);
        }
        __syncthreads();
#pragma unroll
        for (int i = 0; i < 2; ++i) {
            int tt = (threadIdx.x >> 3) + i * 32;
            int c8 = threadIdx.x & 7;
            short tmp[8];
#pragma unroll
            for (int j = 0; j < 8; ++j) {
                __hip_bfloat16 v = tile[c8 * 8 + j][tt];
                tmp[j] = *reinterpret_cast<short*>(&v);
            }
            *reinterpret_cast<bf16x8*>(&xT[((size_t)(b * Tt + t0 + tt)) * Cc + c0 + c8 * 8]) =
                *reinterpret_cast<bf16x8*>(tmp);
        }
    } else {
        int n = (bid - 2048) * 256 + threadIdx.x;     // [0, 4*512*256)
        int c = n & 255;
        int h = (n >> 8) & 511;
        int k = n >> 17;
        Wt[n] = __float2bfloat16(W[h * (Cc * Kk) + c * Kk + k]);
        if (bid == 2048) zeros[threadIdx.x] = 0.f;    // 1 KB zero page
    }
}

// ---------- main: BM=256h x BN=128t, 4 waves (2Mx2N -> 128x64/wave), BK=32 ----------
// K-order: conv-k inner (kappa = s&3), ch-block outer (cs = (s>>2)*32); 32 steps.
// A: 3 bufs x [256 rows][4 slots x 16B] = 3 x 16384. B: 2 bufs x [192 rows][4 x 16B],
// one B buf serves 4 consecutive steps (all kappa via row shifts).
// Swizzle: slot_phys = slot_log ^ ((row>>1)&3) (validated in r6).
#define A_BUF   16384
#define B_BUF   12288
#define B_BASE  49152
#define LDS_TOTAL 73728

#define BAR __builtin_amdgcn_s_barrier()
#define LGKM0 do { asm volatile("s_waitcnt lgkmcnt(0)" ::: "memory"); \
                   __builtin_amdgcn_sched_barrier(0); } while (0)

__global__ __launch_bounds__(256, 2) void conv_mfma_kernel(
    const __hip_bfloat16* __restrict__ xT,
    const __hip_bfloat16* __restrict__ Wt,
    const float* __restrict__ bias,
    const float* __restrict__ zeros,
    float* __restrict__ out)
{
    __shared__ __align__(1024) char smem[LDS_TOTAL];
    const int tid = threadIdx.x, lane = tid & 63, wave = tid >> 6;
    const int wr = wave >> 1, wc = wave & 1;          // 2(M h) x 2(N t)
    const int l15 = lane & 15, lg = lane >> 4;

    // XCD-bijective swizzle: 512 blocks, XCD x <-> batch x (2MB xT slice L2-resident)
    const int flat = blockIdx.x + 32 * blockIdx.y + 64 * blockIdx.z;
    const int swz  = (flat & 7) * 64 + (flat >> 3);
    const int t0 = (swz & 31) * 128;
    const int h0 = ((swz >> 5) & 1) * 256;
    const int b  = swz >> 6;

    const char* Wt_c = (const char*)Wt;
    const char* xT_c = (const char*)xT;
    const char* zz   = (const char*)zeros;

    // ---- staging descriptors (linear LDS dst; swizzle folded into global src) ----
    const char* abase[4]; int adst_[4];
#pragma unroll
    for (int i = 0; i < 4; ++i) {
        int s = tid + i * 256;                        // 0..1023
        int row = s >> 2, sl = s & 3;
        int colch = (sl ^ ((row >> 1) & 3)) * 8;
        abase[i] = Wt_c + (((size_t)(h0 + row)) * Cc + colch) * 2;
        adst_[i] = s * 16;
    }
    const char* bbase[3]; int bdst_[3];
#pragma unroll
    for (int i = 0; i < 3; ++i) {
        int s = tid + i * 256;                        // 0..767, rows 0..191
        int row = s >> 2, sl = s & 3;
        int colch = (sl ^ ((row >> 1) & 3)) * 8;
        int tg = t0 - 3 + row;
        bool valid = (row <= 130) && (tg >= 0);
        bbase[i] = valid ? xT_c + (((size_t)b * Tt + tg) * Cc + colch) * 2
                         : zz + (s & 31) * 16;
        bdst_[i] = s * 16;
    }

    // ---- fragment read offsets (r6-validated swizzle) ----
    const int aoff0 = (wr * 128 + l15) * 64 + ((lg ^ ((l15 >> 1) & 3)) << 4);
    int btab[4];
#pragma unroll
    for (int k = 0; k < 4; ++k)
        btab[k] = (wc * 64 + l15 + k) * 64 + ((lg ^ (((l15 + k) >> 1) & 3)) << 4);

    char *A0 = smem, *A1 = smem + A_BUF, *A2 = smem + 2 * A_BUF;
    char *B0 = smem + B_BASE, *B1 = smem + B_BASE + B_BUF;

    // ---- prologue: A(0), B(cs0), A(1); keep A(1) in flight ----
#pragma unroll
    for (int i = 0; i < 4; ++i) gload16(abase[i], A0 + adst_[i]);
#pragma unroll
    for (int i = 0; i < 3; ++i) gload16(bbase[i], B0 + bdst_[i]);
#pragma unroll
    for (int i = 0; i < 4; ++i) gload16(abase[i] + 262144, A1 + adst_[i]);
    asm volatile("s_waitcnt vmcnt(4)" ::: "memory");
    BAR;

    f32x4 acc[8][4] = {};

#pragma unroll 4
    for (int s = 0; s < 32; ++s) {
        const int kap = s & 3;
        const int bo  = (kap == 0) ? btab[0] : (kap == 1) ? btab[1]
                      : (kap == 2) ? btab[2] : btab[3];

        bf16x8 a_[4], b_[4];
        // -- P0: A fm0-3 + B (shared across both phases) --
#pragma unroll
        for (int fm = 0; fm < 4; ++fm) a_[fm] = *(const bf16x8*)(A0 + aoff0 + fm * 1024);
#pragma unroll
        for (int ft = 0; ft < 4; ++ft) b_[ft] = *(const bf16x8*)(B0 + bo + ft * 1024);
        if (s < 30) {                                 // stage A(s+2) into A2
            const long au = (long)((s + 2) & 3) * 262144 + (long)((s + 2) >> 2) * 64;
#pragma unroll
            for (int i = 0; i < 4; ++i) gload16(abase[i] + au, A2 + adst_[i]);
        }
        BAR; LGKM0;
        __builtin_amdgcn_s_setprio(1);
#pragma unroll
        for (int fm = 0; fm < 4; ++fm)
#pragma unroll
            for (int ft = 0; ft < 4; ++ft)
                acc[fm][ft] = __builtin_amdgcn_mfma_f32_16x16x32_bf16(a_[fm], b_[ft], acc[fm][ft], 0, 0, 0);
        __builtin_amdgcn_s_setprio(0);
        BAR;
        // -- P1: A fm4-7 (reuses b_) --
#pragma unroll
        for (int fm = 0; fm < 4; ++fm) a_[fm] = *(const bf16x8*)(A0 + aoff0 + (fm + 4) * 1024);
        if (kap == 0 && s < 28) {                     // stage next B ch-block into B1
            const long bu = (long)((s >> 2) + 1) * 64;
#pragma unroll
            for (int i = 0; i < 3; ++i) gload16(bbase[i] + bu, B1 + bdst_[i]);
        }
        BAR; LGKM0;
        __builtin_amdgcn_s_setprio(1);
#pragma unroll
        for (int fm = 0; fm < 4; ++fm)
#pragma unroll
            for (int ft = 0; ft < 4; ++ft)
                acc[fm + 4][ft] = __builtin_amdgcn_mfma_f32_16x16x32_bf16(a_[fm], b_[ft], acc[fm + 4][ft], 0, 0, 0);
        __builtin_amdgcn_s_setprio(0);
        // counted vmcnt: keep this step's issues in flight, drain older
        if (s < 30) {
            if (kap == 0 && s < 28) asm volatile("s_waitcnt vmcnt(7)" ::: "memory");
            else                    asm volatile("s_waitcnt vmcnt(4)" ::: "memory");
        } else if (s == 30)         asm volatile("s_waitcnt vmcnt(0)" ::: "memory");
        BAR;
        // rotate buffers
        char* tp = A0; A0 = A1; A1 = A2; A2 = tp;
        if (kap == 3) { char* up = B0; B0 = B1; B1 = up; }
    }

    // ---- epilogue: D col=l15 -> t, row=lg*4+q -> h (r6-validated) ----
#pragma unroll
    for (int fm = 0; fm < 8; ++fm) {
        int hb = h0 + wr * 128 + fm * 16 + lg * 4;
        float4 bs = *(const float4*)&bias[hb];
        const float* bsp = (const float*)&bs;
#pragma unroll
        for (int q = 0; q < 4; ++q)
#pragma unroll
            for (int ft = 0; ft < 4; ++ft) {
                int t = t0 + wc * 64 + ft * 16 + l15;
                out[((size_t)(b * Hh + hb + q)) * Tt + t] = acc[fm][ft][q] + bsp[q];
            }
    }
}

// ---------------- fallback (ws too small): fp32 kernel ----------------
#define TT 256
#define HT 8
#define CT 4
__global__ __launch_bounds__(256) void conv1d_f32_kernel(
    const float* __restrict__ x, const float* __restrict__ W,
    const float* __restrict__ bias, float* __restrict__ out)
{
    const int tid = threadIdx.x;
    const int t0 = blockIdx.x * TT;
    const int h0 = blockIdx.y * HT;
    const int b  = blockIdx.z;
    __shared__ float xs[CT][TT + Kk];
    float acc[HT];
#pragma unroll
    for (int h = 0; h < HT; ++h) acc[h] = 0.f;
    const float* xb = x + (size_t)b * Cc * Tt;
    for (int c0 = 0; c0 < Cc; c0 += CT) {
        __syncthreads();
#pragma unroll
        for (int cc = 0; cc < CT; ++cc)
            for (int j = tid; j < TT + Kk - 1; j += 256) {
                int idx = t0 - (Kk - 1) + j;
                xs[cc][j] = (idx >= 0) ? xb[(size_t)(c0 + cc) * Tt + idx] : 0.f;
            }
        __syncthreads();
#pragma unroll
        for (int cc = 0; cc < CT; ++cc) {
            float xv[Kk];
#pragma unroll
            for (int k = 0; k < Kk; ++k) xv[k] = xs[cc][tid + k];
#pragma unroll
            for (int h = 0; h < HT; ++h) {
                const float* wp = W + (size_t)(h0 + h) * (Cc * Kk) + (size_t)(c0 + cc) * Kk;
#pragma unroll
                for (int k = 0; k < Kk; ++k) acc[h] += wp[k] * xv[k];
            }
        }
    }
#pragma unroll
    for (int h = 0; h < HT; ++h)
        out[((size_t)b * Hh + (h0 + h)) * Tt + t0 + tid] = acc[h] + bias[h0 + h];
}

extern "C" void kernel_launch(void* const* d_in, const int* in_sizes, int n_in,
                              void* d_out, int out_size, void* d_ws, size_t ws_size,
                              hipStream_t stream) {
    const float* x    = (const float*)d_in[0];
    const float* W    = (const float*)d_in[1];
    const float* bias = (const float*)d_in[2];
    float* out        = (float*)d_out;

    if (ws_size >= WS_NEEDED) {
        __hip_bfloat16* xT = (__hip_bfloat16*)((char*)d_ws + WS_XT_OFF);
        __hip_bfloat16* Wt = (__hip_bfloat16*)((char*)d_ws + WS_WT_OFF);
        float* zeros       = (float*)((char*)d_ws + WS_ZERO_OFF);

        prep_kernel<<<dim3(4096), dim3(256), 0, stream>>>(x, W, xT, Wt, zeros);
        conv_mfma_kernel<<<dim3(32, 2, 8), dim3(256), 0, stream>>>(xT, Wt, bias, zeros, out);
    } else {
        conv1d_f32_kernel<<<dim3(Tt / TT, Hh / HT, Bb), dim3(256), 0, stream>>>(x, W, bias, out);
    }
}